// Round 2
// baseline (253.606 us; speedup 1.0000x reference)
//
#include <hip/hip_runtime.h>

#define N_NODES 10000
#define N_EDGES 320000
#define E_PAD (N_EDGES + 8 * N_NODES)   // CSR padded to 8-multiples per node

// ---------------------------------------------------------------------------
// fp16 helpers (RNE via v_cvt_f16_f32 / v_cvt_f32_f16)
// ---------------------------------------------------------------------------
__device__ __forceinline__ unsigned short f2h_bits(float v) {
    _Float16 h = (_Float16)v;
    unsigned short u;
    __builtin_memcpy(&u, &h, 2);
    return u;
}
// packed-pair unpack: u32 holds fp16 features (2j, 2j+1) little-endian
__device__ __forceinline__ float h2f_lo(unsigned int g) {
    unsigned short u = (unsigned short)(g & 0xFFFFu);
    _Float16 h; __builtin_memcpy(&h, &u, 2);
    return (float)h;
}
__device__ __forceinline__ float h2f_hi(unsigned int g) {
    unsigned short u = (unsigned short)(g >> 16);
    _Float16 h; __builtin_memcpy(&h, &u, 2);
    return (float)h;
}

// ---------------------------------------------------------------------------
// Fused setup: deg/counts init + CSR zero + x->fp16 + W1/W2 fp16 transpose.
// ---------------------------------------------------------------------------
__global__ __launch_bounds__(256) void setup_kernel(
        float* __restrict__ deg, int* __restrict__ counts,
        int* __restrict__ csr_src, float* __restrict__ csr_w,
        const float* __restrict__ x, unsigned short* __restrict__ xh,
        const float* __restrict__ W1, unsigned short* __restrict__ w1t,
        const float* __restrict__ W2, unsigned short* __restrict__ w2t) {
    int i = blockIdx.x * 256 + threadIdx.x;
    const int S0 = N_NODES;                  // deg/counts
    const int S1 = S0 + E_PAD;               // csr zero
    const int S2 = S1 + N_NODES * 256;       // x -> fp16
    const int S3 = S2 + 256 * 512;           // W1
    const int S4 = S3 + 512 * 768;           // W2
    if (i < S0) {
        deg[i] = 1.0f; counts[i] = 0;        // self-loop weight 1
    } else if (i < S1) {
        int j = i - S0;
        csr_src[j] = 0; csr_w[j] = 0.f;      // pad edges: node 0, weight 0
    } else if (i < S2) {
        int j = i - S1;
        xh[j] = f2h_bits(x[j]);
    } else if (i < S3) {
        int j = i - S2;
        int k = j >> 9, n = j & 511;         // W1 [256][512]
        w1t[n * 256 + k] = f2h_bits(W1[j]);
    } else if (i < S4) {
        int j = i - S3;
        int k = j / 768, n = j - k * 768;    // W2 [512][768]
        w2t[n * 512 + k] = f2h_bits(W2[j]);
    }
}

// Degree + count: counts[c] = in-degree (excl. self), deg[c] = weighted degree.
__global__ __launch_bounds__(256) void count_kernel(const int* __restrict__ col,
                                                    const float* __restrict__ ew,
                                                    float* __restrict__ deg,
                                                    int* __restrict__ counts, int e) {
    int i = blockIdx.x * 256 + threadIdx.x;
    if (i < e) {
        int c = col[i];
        atomicAdd(counts + c, 1);
        atomicAdd(deg + c, ew[i]);
    }
}

// Single-block scan, 2 barriers: each thread owns 10 contiguous counts
// (local serial prefix), then wave-scan + 16-partial block scan.
// Emits 8-padded exclusive ptr + fused dinv.
__global__ __launch_bounds__(1024) void scan_dinv_kernel(const int* __restrict__ counts,
                                                         int* __restrict__ ptr,
                                                         const float* __restrict__ deg,
                                                         float* __restrict__ dinv, int n) {
    __shared__ int wsum[16];
    __shared__ int woff[16];
    const int t = (int)threadIdx.x;
    const int lane = t & 63;
    const int wid = t >> 6;
    const int base = t * 10;
    int loc[10];
    int tot = 0;
#pragma unroll
    for (int q = 0; q < 10; ++q) {
        int i = base + q;
        int v = 0;
        if (i < n) {
            v = (counts[i] + 7) & ~7;        // pad to multiple of 8
            float d = deg[i];
            dinv[i] = (d > 0.0f) ? rsqrtf(d) : 0.0f;
        }
        loc[q] = tot;                        // exclusive local prefix
        tot += v;
    }
    int x = tot;                             // wave-inclusive scan of totals
#pragma unroll
    for (int off = 1; off < 64; off <<= 1) {
        int u = __shfl_up(x, off);
        if (lane >= off) x += u;
    }
    if (lane == 63) wsum[wid] = x;
    __syncthreads();                         // B1
    if (wid == 0 && lane < 16) {
        int s = wsum[lane];
        int y = s;
#pragma unroll
        for (int off = 1; off < 16; off <<= 1) {
            int u = __shfl_up(y, off);
            if (lane >= off) y += u;
        }
        woff[lane] = y - s;                  // exclusive wave offsets
        if (lane == 15) ptr[n] = y;          // grand total
    }
    __syncthreads();                         // B2
    const int tbase = woff[wid] + (x - tot); // thread's exclusive offset
#pragma unroll
    for (int q = 0; q < 10; ++q) {
        int i = base + q;
        if (i < n) ptr[i] = tbase + loc[q];
    }
}

// Scatter: slot recovered by atomicSub on counts (dead after scan) -> no slot
// array.  Segment order is reversed vs arrival; irrelevant for a sum.
__global__ __launch_bounds__(256) void scatter_kernel(const int* __restrict__ row,
                                                      const int* __restrict__ col,
                                                      const float* __restrict__ ew,
                                                      const float* __restrict__ dinv,
                                                      const int* __restrict__ ptr,
                                                      int* __restrict__ counts,
                                                      int* __restrict__ csr_src,
                                                      float* __restrict__ csr_w, int e) {
    int i = blockIdx.x * 256 + threadIdx.x;
    if (i < e) {
        int c = col[i], r = row[i];
        int sl = atomicSub(counts + c, 1) - 1;
        int pos = ptr[c] + sl;
        csr_src[pos] = r;
        csr_w[pos] = dinv[r] * ew[i] * dinv[c];
    }
}

// ---------------------------------------------------------------------------
// XCD-sliced aggregation over PACKED fp16 activations, fp16 output:
//   acc[n,f] = dinv[n]^2 * x[n,f] + sum_in w * x[src,f]   (fp32 accumulate)
// One wave per (node, 64-PAIR slice = 128 features); lane = one u32 pair.
// 256-thread blocks, 4 wave-units each: 64-thr blocks cap at 16 wg/CU = 16
// waves/CU; 256-thr blocks reach 32 waves/CU (2x latency hiding).
// node via readfirstlane -> scalar metadata / gather bases stay in SGPRs.
// 16-edge unroll: 16 gathers in flight; CSR read as int4/float4 s_loads.
// Slab per slice = 10000 x 128 x 2B = 2.56 MB < 4 MB per-XCD L2.
// ---------------------------------------------------------------------------
template <int F, int SSHIFT>
__global__ __launch_bounds__(256, 8) void agg_slice_kernel(const unsigned int* __restrict__ xpk,
                                                           const int* __restrict__ ptr,
                                                           const int* __restrict__ csr_src,
                                                           const float* __restrict__ csr_w,
                                                           const float* __restrict__ dinv,
                                                           unsigned int* __restrict__ o) {
    constexpr int F2 = F / 2;
    const int unit = __builtin_amdgcn_readfirstlane((int)blockIdx.x * 4 + ((int)threadIdx.x >> 6));
    const int slice = unit & ((1 << SSHIFT) - 1);
    const int node = unit >> SSHIFT;              // scalar
    const int lane = (int)threadIdx.x & 63;
    const int f2 = slice * 64 + lane;             // pair index
    const float di = dinv[node];
    const float si = di * di;
    unsigned int gs = xpk[node * F2 + f2];
    float acc0 = si * h2f_lo(gs);
    float acc1 = si * h2f_hi(gs);
    const int s = ptr[node], e = ptr[node + 1];   // 8-aligned, length % 8 == 0

    int j = s;
    for (; j + 16 <= e; j += 16) {
        int4   sa = *(const int4*)(csr_src + j);
        int4   sb = *(const int4*)(csr_src + j + 4);
        int4   sc = *(const int4*)(csr_src + j + 8);
        int4   sd = *(const int4*)(csr_src + j + 12);
        float4 wa = *(const float4*)(csr_w + j);
        float4 wb = *(const float4*)(csr_w + j + 4);
        float4 wc = *(const float4*)(csr_w + j + 8);
        float4 wd = *(const float4*)(csr_w + j + 12);
        unsigned int g0 = xpk[sa.x * F2 + f2];
        unsigned int g1 = xpk[sa.y * F2 + f2];
        unsigned int g2 = xpk[sa.z * F2 + f2];
        unsigned int g3 = xpk[sa.w * F2 + f2];
        unsigned int g4 = xpk[sb.x * F2 + f2];
        unsigned int g5 = xpk[sb.y * F2 + f2];
        unsigned int g6 = xpk[sb.z * F2 + f2];
        unsigned int g7 = xpk[sb.w * F2 + f2];
        unsigned int g8 = xpk[sc.x * F2 + f2];
        unsigned int g9 = xpk[sc.y * F2 + f2];
        unsigned int gA = xpk[sc.z * F2 + f2];
        unsigned int gB = xpk[sc.w * F2 + f2];
        unsigned int gC = xpk[sd.x * F2 + f2];
        unsigned int gD = xpk[sd.y * F2 + f2];
        unsigned int gE = xpk[sd.z * F2 + f2];
        unsigned int gF = xpk[sd.w * F2 + f2];
        acc0 += wa.x * h2f_lo(g0) + wa.y * h2f_lo(g1) + wa.z * h2f_lo(g2) + wa.w * h2f_lo(g3);
        acc1 += wa.x * h2f_hi(g0) + wa.y * h2f_hi(g1) + wa.z * h2f_hi(g2) + wa.w * h2f_hi(g3);
        acc0 += wb.x * h2f_lo(g4) + wb.y * h2f_lo(g5) + wb.z * h2f_lo(g6) + wb.w * h2f_lo(g7);
        acc1 += wb.x * h2f_hi(g4) + wb.y * h2f_hi(g5) + wb.z * h2f_hi(g6) + wb.w * h2f_hi(g7);
        acc0 += wc.x * h2f_lo(g8) + wc.y * h2f_lo(g9) + wc.z * h2f_lo(gA) + wc.w * h2f_lo(gB);
        acc1 += wc.x * h2f_hi(g8) + wc.y * h2f_hi(g9) + wc.z * h2f_hi(gA) + wc.w * h2f_hi(gB);
        acc0 += wd.x * h2f_lo(gC) + wd.y * h2f_lo(gD) + wd.z * h2f_lo(gE) + wd.w * h2f_lo(gF);
        acc1 += wd.x * h2f_hi(gC) + wd.y * h2f_hi(gD) + wd.z * h2f_hi(gE) + wd.w * h2f_hi(gF);
    }
    if (j < e) {                                  // one 8-wide tail
        int4   sa = *(const int4*)(csr_src + j);
        int4   sb = *(const int4*)(csr_src + j + 4);
        float4 wa = *(const float4*)(csr_w + j);
        float4 wb = *(const float4*)(csr_w + j + 4);
        unsigned int g0 = xpk[sa.x * F2 + f2];
        unsigned int g1 = xpk[sa.y * F2 + f2];
        unsigned int g2 = xpk[sa.z * F2 + f2];
        unsigned int g3 = xpk[sa.w * F2 + f2];
        unsigned int g4 = xpk[sb.x * F2 + f2];
        unsigned int g5 = xpk[sb.y * F2 + f2];
        unsigned int g6 = xpk[sb.z * F2 + f2];
        unsigned int g7 = xpk[sb.w * F2 + f2];
        acc0 += wa.x * h2f_lo(g0) + wa.y * h2f_lo(g1) + wa.z * h2f_lo(g2) + wa.w * h2f_lo(g3);
        acc1 += wa.x * h2f_hi(g0) + wa.y * h2f_hi(g1) + wa.z * h2f_hi(g2) + wa.w * h2f_hi(g3);
        acc0 += wb.x * h2f_lo(g4) + wb.y * h2f_lo(g5) + wb.z * h2f_lo(g6) + wb.w * h2f_lo(g7);
        acc1 += wb.x * h2f_hi(g4) + wb.y * h2f_hi(g5) + wb.z * h2f_hi(g6) + wb.w * h2f_hi(g7);
    }

    unsigned short h0 = f2h_bits(acc0);
    unsigned short h1 = f2h_bits(acc1);
    o[node * F2 + f2] = ((unsigned int)h1 << 16) | h0;
}

// ---------------------------------------------------------------------------
// fp16 MFMA GEMM + bias + relu, async global->LDS staging, fp16 output.
//   C[M,N] = A[M,K] @ B[K,N] + bias   (fp32 accumulate, single pass)
// B transposed as Bt[N][K]; A row-padded to TM multiple (pad rows discarded).
// Tile 128m x 128n, BK=32, 256 threads = 4 waves of 64m x 64n.
// LDS 16KB/buf x 2 = 32KB -> 3 blocks/CU.
// ---------------------------------------------------------------------------
typedef _Float16 half8 __attribute__((ext_vector_type(8)));
typedef float f32x4 __attribute__((ext_vector_type(4)));

#define TM 128
#define TN 128
#define BK 32
#define LDS_A 0
#define LDS_B 8192
#define LDS_BUF 16384

__device__ __forceinline__ void async16(const unsigned short* g, unsigned char* l) {
    __builtin_amdgcn_global_load_lds(
        (const __attribute__((address_space(1))) unsigned int*)g,
        (__attribute__((address_space(3))) unsigned int*)l, 16, 0, 0);
}

__global__ __launch_bounds__(256, 3) void gemm_mfma_kernel(
        const unsigned short* __restrict__ A,
        const unsigned short* __restrict__ Bt,
        const float* __restrict__ bias,
        unsigned short* __restrict__ Cb,
        int M, int K, int N) {
    __shared__ unsigned char lds[2 * LDS_BUF];
    const int t = (int)threadIdx.x;

    // bijective XCD-chunked remap (m204): same-row-panel tiles share an XCD L2
    const int gx = (int)gridDim.x;
    const int nwg = gx * (int)gridDim.y;
    const int lin = (int)blockIdx.y * gx + (int)blockIdx.x;
    const int xcd = lin & 7, idx = lin >> 3;
    const int q = nwg >> 3, r = nwg & 7;
    const int logi = (xcd < r ? xcd * (q + 1) : r * (q + 1) + (xcd - r) * q) + idx;
    const int bm = (logi / gx) * TM;
    const int bn = (logi % gx) * TN;

    const int lane = t & 63;
    const int wave = t >> 6;
    const int wm = (wave & 1) * 64;
    const int wn = (wave >> 1) * 64;

    // ---- staging geometry (per lane): 16-row blocks, 1024 B per async issue ----
    const int slr = lane >> 2;                       // 0..15 local row
    const int scc = (lane & 3) ^ ((slr >> 1) & 3);   // swizzled global chunk
    const int bi0 = wave * 2, bi1 = wave * 2 + 1;    // 16-row block ids (0..7)
    const unsigned short* gA0 = A + (size_t)(bm + bi0 * 16 + slr) * K + scc * 8;
    const unsigned short* gA1 = A + (size_t)(bm + bi1 * 16 + slr) * K + scc * 8;
    const unsigned short* gB0 = Bt + (size_t)(bn + bi0 * 16 + slr) * K + scc * 8;
    const unsigned short* gB1 = Bt + (size_t)(bn + bi1 * 16 + slr) * K + scc * 8;

    // ---- fragment read geometry ----
    const int quad = lane >> 4;
    const int lr16 = lane & 15;
    const int fs = (quad ^ ((lr16 >> 1) & 3)) * 16;  // swizzled slot byte offset

    f32x4 acc[4][4];
    const f32x4 zero4 = {0.f, 0.f, 0.f, 0.f};
#pragma unroll
    for (int i = 0; i < 4; ++i)
#pragma unroll
        for (int j = 0; j < 4; ++j) acc[i][j] = zero4;

    const int KT = K / BK;

    auto stage = [&](int kt, int buf) {
        const int k0 = kt * BK;
        unsigned char* b = &lds[buf * LDS_BUF];
        async16(gA0 + k0, b + LDS_A + bi0 * 1024);
        async16(gA1 + k0, b + LDS_A + bi1 * 1024);
        async16(gB0 + k0, b + LDS_B + bi0 * 1024);
        async16(gB1 + k0, b + LDS_B + bi1 * 1024);
    };

    stage(0, 0);
    __syncthreads();

    for (int kt = 0; kt < KT; ++kt) {
        const int buf = kt & 1;
        if (kt + 1 < KT) stage(kt + 1, buf ^ 1);   // async, drains at barrier below

        unsigned char* b = &lds[buf * LDS_BUF];
        half8 av[4], bv[4];
#pragma unroll
        for (int i = 0; i < 4; ++i) {
            int ro = (wm + i * 16 + lr16) * 64 + fs;
            av[i] = *(const half8*)(b + LDS_A + ro);
        }
#pragma unroll
        for (int j = 0; j < 4; ++j) {
            int ro = (wn + j * 16 + lr16) * 64 + fs;
            bv[j] = *(const half8*)(b + LDS_B + ro);
        }
#pragma unroll
        for (int i = 0; i < 4; ++i)
#pragma unroll
            for (int j = 0; j < 4; ++j)
                acc[i][j] = __builtin_amdgcn_mfma_f32_16x16x32_f16(av[i], bv[j], acc[i][j], 0, 0, 0);
        __syncthreads();
    }

    // epilogue: bias + relu, store fp16
    float bcol[4];
#pragma unroll
    for (int j = 0; j < 4; ++j) bcol[j] = bias[bn + wn + j * 16 + lr16];
#pragma unroll
    for (int i = 0; i < 4; ++i) {
#pragma unroll
        for (int r2 = 0; r2 < 4; ++r2) {
            int m = bm + wm + i * 16 + quad * 4 + r2;
            if (m < M) {
#pragma unroll
                for (int j = 0; j < 4; ++j) {
                    float vv = fmaxf(acc[i][j][r2] + bcol[j], 0.f);
                    Cb[(size_t)m * N + bn + wn + j * 16 + lr16] = f2h_bits(vv);
                }
            }
        }
    }
}

// ---------------------------------------------------------------------------
// GEMM for layer 3: N=8, K=768, A packed fp16 pairs.  One wave per row,
// 4 rows per 256-thr block (wg/CU-limit fix).
// ---------------------------------------------------------------------------
__global__ __launch_bounds__(256) void gemm_n8_kernel(const unsigned int* __restrict__ Apk,
                                                      const float* __restrict__ B,
                                                      float* __restrict__ C) {
    const int m = __builtin_amdgcn_readfirstlane((int)blockIdx.x * 4 + ((int)threadIdx.x >> 6));
    const int lane = (int)threadIdx.x & 63;
    const unsigned int* a = Apk + m * 384;   // 384 pairs = 768 feats
    float acc[8] = {};
#pragma unroll
    for (int it = 0; it < 6; ++it) {
        int j2 = lane + it * 64;
        unsigned int av = a[j2];
        float a0 = h2f_lo(av), a1 = h2f_hi(av);
        const float* B0 = B + (size_t)(2 * j2) * 8;
        float4 p0 = *(const float4*)(B0);
        float4 p1 = *(const float4*)(B0 + 4);
        float4 q0 = *(const float4*)(B0 + 8);
        float4 q1 = *(const float4*)(B0 + 12);
        acc[0] += a0 * p0.x + a1 * q0.x; acc[1] += a0 * p0.y + a1 * q0.y;
        acc[2] += a0 * p0.z + a1 * q0.z; acc[3] += a0 * p0.w + a1 * q0.w;
        acc[4] += a0 * p1.x + a1 * q1.x; acc[5] += a0 * p1.y + a1 * q1.y;
        acc[6] += a0 * p1.z + a1 * q1.z; acc[7] += a0 * p1.w + a1 * q1.w;
    }
#pragma unroll
    for (int off = 32; off > 0; off >>= 1) {
#pragma unroll
        for (int i = 0; i < 8; ++i) acc[i] += __shfl_down(acc[i], off);
    }
    if (lane == 0) {
#pragma unroll
        for (int i = 0; i < 8; ++i) C[(size_t)m * 8 + i] = acc[i];
    }
}

// Aggregation for fout=8 (final layer, +bias): one wave per node, lanes split
// edges; 4 nodes per 256-thr block.
__global__ __launch_bounds__(256) void agg8_kernel(const float* __restrict__ xw,
                                                   const int* __restrict__ ptr,
                                                   const int* __restrict__ csr_src,
                                                   const float* __restrict__ csr_w,
                                                   const float* __restrict__ dinv,
                                                   const float* __restrict__ bias,
                                                   float* __restrict__ out) {
    const int node = __builtin_amdgcn_readfirstlane((int)blockIdx.x * 4 + ((int)threadIdx.x >> 6));
    const int lane = (int)threadIdx.x & 63;
    float acc[8] = {};
    int s = ptr[node], e = ptr[node + 1];
    for (int j = s + lane; j < e; j += 64) {
        int src = csr_src[j];
        float w = csr_w[j];
        float4 g0 = *(const float4*)(xw + (size_t)src * 8);
        float4 g1 = *(const float4*)(xw + (size_t)src * 8 + 4);
        acc[0] += w * g0.x; acc[1] += w * g0.y; acc[2] += w * g0.z; acc[3] += w * g0.w;
        acc[4] += w * g1.x; acc[5] += w * g1.y; acc[6] += w * g1.z; acc[7] += w * g1.w;
    }
#pragma unroll
    for (int off = 32; off > 0; off >>= 1) {
#pragma unroll
        for (int i = 0; i < 8; ++i) acc[i] += __shfl_down(acc[i], off);
    }
    if (lane == 0) {
        float di = dinv[node];
        float si = di * di;
#pragma unroll
        for (int i = 0; i < 8; ++i)
            out[(size_t)node * 8 + i] = acc[i] + si * xw[(size_t)node * 8 + i] + bias[i];
    }
}

// ---------------------------------------------------------------------------

extern "C" void kernel_launch(void* const* d_in, const int* in_sizes, int n_in,
                              void* d_out, int out_size, void* d_ws, size_t ws_size,
                              hipStream_t stream) {
    const int N = N_NODES, E = N_EDGES;
    const int N_PAD = ((N + TM - 1) / TM) * TM;   // 10112
    const float* x   = (const float*)d_in[0];
    const int*   ei  = (const int*)d_in[1];   // [2, E] (row=source, col=target)
    const float* ew  = (const float*)d_in[2];
    const float* W1  = (const float*)d_in[3];
    const float* b1  = (const float*)d_in[4];
    const float* W2  = (const float*)d_in[5];
    const float* b2  = (const float*)d_in[6];
    const float* W3  = (const float*)d_in[7];
    const float* b3  = (const float*)d_in[8];
    float* out = (float*)d_out;

    const int* row = ei;        // source
    const int* col = ei + E;    // target

    // workspace layout (256B-aligned); ~46 MB total
    char* ws = (char*)d_ws;
    size_t off = 0;
    auto alloc = [&](size_t bytes) {
        void* p = ws + off;
        off += (bytes + 255) & ~(size_t)255;
        return p;
    };
    float*          deg     = (float*)alloc((size_t)N * 4);
    float*          dinv    = (float*)alloc((size_t)N * 4);
    int*            counts  = (int*)alloc((size_t)N * 4);
    int*            col_ptr = (int*)alloc((size_t)(N + 1) * 4);
    int*            csr_src = (int*)alloc((size_t)E_PAD * 4);
    float*          csr_w   = (float*)alloc((size_t)E_PAD * 4);
    unsigned short* xh      = (unsigned short*)alloc((size_t)N * 256 * 2);   // x as fp16
    unsigned short* h1h     = (unsigned short*)alloc((size_t)N * 512 * 2);   // gemm1 out fp16
    unsigned short* h2h     = (unsigned short*)alloc((size_t)N * 768 * 2);   // gemm2 out fp16
    unsigned short* Aagg    = (unsigned short*)alloc((size_t)N_PAD * 512 * 2); // agg out (both layers)
    unsigned short* W1t     = (unsigned short*)alloc((size_t)512 * 256 * 2);
    unsigned short* W2t     = (unsigned short*)alloc((size_t)768 * 512 * 2);
    float*          xw8     = (float*)alloc((size_t)N * 8 * 4);
    (void)ws_size;

    int nb_edges = (E + 255) / 256;

    // --- fused setup (init + CSR zero + x->fp16 + weight conversion) ---
    {
        int tot = N + E_PAD + N * 256 + 256 * 512 + 512 * 768;
        setup_kernel<<<(tot + 255) / 256, 256, 0, stream>>>(
            deg, counts, csr_src, csr_w, x, xh, W1, W1t, W2, W2t);
    }
    count_kernel<<<nb_edges, 256, 0, stream>>>(col, ew, deg, counts, E);
    scan_dinv_kernel<<<1, 1024, 0, stream>>>(counts, col_ptr, deg, dinv, N);
    scatter_kernel<<<nb_edges, 256, 0, stream>>>(row, col, ew, dinv, col_ptr, counts,
                                                 csr_src, csr_w, E);

    // --- layer 1: agg(fp16 x, 2 slices) -> gemm 256->512 (+b1, relu, fp16 out)
    agg_slice_kernel<256, 1><<<N * 2 / 4, 256, 0, stream>>>(
        (const unsigned int*)xh, col_ptr, csr_src, csr_w, dinv, (unsigned int*)Aagg);
    {
        dim3 grid(512 / TN, N_PAD / TM);
        gemm_mfma_kernel<<<grid, 256, 0, stream>>>(Aagg, W1t, b1, h1h, N, 256, 512);
    }
    // --- layer 2: agg(fp16 h1, 4 slices) -> gemm 512->768 (+b2, relu, fp16 out)
    agg_slice_kernel<512, 2><<<N * 4 / 4, 256, 0, stream>>>(
        (const unsigned int*)h1h, col_ptr, csr_src, csr_w, dinv, (unsigned int*)Aagg);
    {
        dim3 grid(768 / TN, N_PAD / TM);
        gemm_mfma_kernel<<<grid, 256, 0, stream>>>(Aagg, W2t, b2, h2h, N, 512, 768);
    }
    // --- layer 3: gemm 768->8 (packed fp16 A) -> agg8 (+b3) ---
    gemm_n8_kernel<<<N / 4, 256, 0, stream>>>((const unsigned int*)h2h, W3, xw8);
    agg8_kernel<<<N / 4, 256, 0, stream>>>(xw8, col_ptr, csr_src, csr_w, dinv, b3, out);

    (void)out_size; (void)n_in; (void)in_sizes;
}

// Round 3
// 249.080 us; speedup vs baseline: 1.0182x; 1.0182x over previous
//
#include <hip/hip_runtime.h>

#define N_NODES 10000
#define N_EDGES 320000
#define E_PAD (N_EDGES + 8 * N_NODES)   // CSR padded to 8-multiples per node

// ---------------------------------------------------------------------------
// fp16 helpers (RNE via v_cvt_f16_f32 / v_cvt_f32_f16)
// ---------------------------------------------------------------------------
__device__ __forceinline__ unsigned short f2h_bits(float v) {
    _Float16 h = (_Float16)v;
    unsigned short u;
    __builtin_memcpy(&u, &h, 2);
    return u;
}
// packed-pair unpack: u32 holds fp16 features (2j, 2j+1) little-endian
__device__ __forceinline__ float h2f_lo(unsigned int g) {
    unsigned short u = (unsigned short)(g & 0xFFFFu);
    _Float16 h; __builtin_memcpy(&h, &u, 2);
    return (float)h;
}
__device__ __forceinline__ float h2f_hi(unsigned int g) {
    unsigned short u = (unsigned short)(g >> 16);
    _Float16 h; __builtin_memcpy(&h, &u, 2);
    return (float)h;
}

// ---------------------------------------------------------------------------
// Fused setup: deg/counts init + CSR zero + x->fp16 + W1/W2 fp16 transpose.
// ---------------------------------------------------------------------------
__global__ __launch_bounds__(256) void setup_kernel(
        float* __restrict__ deg, int* __restrict__ counts,
        int* __restrict__ csr_src, float* __restrict__ csr_w,
        const float* __restrict__ x, unsigned short* __restrict__ xh,
        const float* __restrict__ W1, unsigned short* __restrict__ w1t,
        const float* __restrict__ W2, unsigned short* __restrict__ w2t) {
    int i = blockIdx.x * 256 + threadIdx.x;
    const int S0 = N_NODES;                  // deg/counts
    const int S1 = S0 + E_PAD;               // csr zero
    const int S2 = S1 + N_NODES * 256;       // x -> fp16
    const int S3 = S2 + 256 * 512;           // W1
    const int S4 = S3 + 512 * 768;           // W2
    if (i < S0) {
        deg[i] = 1.0f; counts[i] = 0;        // self-loop weight 1
    } else if (i < S1) {
        int j = i - S0;
        csr_src[j] = 0; csr_w[j] = 0.f;      // pad edges: node 0, weight 0
    } else if (i < S2) {
        int j = i - S1;
        xh[j] = f2h_bits(x[j]);
    } else if (i < S3) {
        int j = i - S2;
        int k = j >> 9, n = j & 511;         // W1 [256][512]
        w1t[n * 256 + k] = f2h_bits(W1[j]);
    } else if (i < S4) {
        int j = i - S3;
        int k = j / 768, n = j - k * 768;    // W2 [512][768]
        w2t[n * 512 + k] = f2h_bits(W2[j]);
    }
}

// Degree + count: counts[c] = in-degree (excl. self), deg[c] = weighted degree.
__global__ __launch_bounds__(256) void count_kernel(const int* __restrict__ col,
                                                    const float* __restrict__ ew,
                                                    float* __restrict__ deg,
                                                    int* __restrict__ counts, int e) {
    int i = blockIdx.x * 256 + threadIdx.x;
    if (i < e) {
        int c = col[i];
        atomicAdd(counts + c, 1);
        atomicAdd(deg + c, ew[i]);
    }
}

// Single-block scan, 2 barriers: each thread owns 10 contiguous counts
// (local serial prefix), then wave-scan + 16-partial block scan.
// Emits 8-padded exclusive ptr + fused dinv.
__global__ __launch_bounds__(1024) void scan_dinv_kernel(const int* __restrict__ counts,
                                                         int* __restrict__ ptr,
                                                         const float* __restrict__ deg,
                                                         float* __restrict__ dinv, int n) {
    __shared__ int wsum[16];
    __shared__ int woff[16];
    const int t = (int)threadIdx.x;
    const int lane = t & 63;
    const int wid = t >> 6;
    const int base = t * 10;
    int loc[10];
    int tot = 0;
#pragma unroll
    for (int q = 0; q < 10; ++q) {
        int i = base + q;
        int v = 0;
        if (i < n) {
            v = (counts[i] + 7) & ~7;        // pad to multiple of 8
            float d = deg[i];
            dinv[i] = (d > 0.0f) ? rsqrtf(d) : 0.0f;
        }
        loc[q] = tot;                        // exclusive local prefix
        tot += v;
    }
    int x = tot;                             // wave-inclusive scan of totals
#pragma unroll
    for (int off = 1; off < 64; off <<= 1) {
        int u = __shfl_up(x, off);
        if (lane >= off) x += u;
    }
    if (lane == 63) wsum[wid] = x;
    __syncthreads();                         // B1
    if (wid == 0 && lane < 16) {
        int s = wsum[lane];
        int y = s;
#pragma unroll
        for (int off = 1; off < 16; off <<= 1) {
            int u = __shfl_up(y, off);
            if (lane >= off) y += u;
        }
        woff[lane] = y - s;                  // exclusive wave offsets
        if (lane == 15) ptr[n] = y;          // grand total
    }
    __syncthreads();                         // B2
    const int tbase = woff[wid] + (x - tot); // thread's exclusive offset
#pragma unroll
    for (int q = 0; q < 10; ++q) {
        int i = base + q;
        if (i < n) ptr[i] = tbase + loc[q];
    }
}

// Scatter: slot recovered by atomicSub on counts (dead after scan) -> no slot
// array.  Segment order is reversed vs arrival; irrelevant for a sum.
__global__ __launch_bounds__(256) void scatter_kernel(const int* __restrict__ row,
                                                      const int* __restrict__ col,
                                                      const float* __restrict__ ew,
                                                      const float* __restrict__ dinv,
                                                      const int* __restrict__ ptr,
                                                      int* __restrict__ counts,
                                                      int* __restrict__ csr_src,
                                                      float* __restrict__ csr_w, int e) {
    int i = blockIdx.x * 256 + threadIdx.x;
    if (i < e) {
        int c = col[i], r = row[i];
        int sl = atomicSub(counts + c, 1) - 1;
        int pos = ptr[c] + sl;
        csr_src[pos] = r;
        csr_w[pos] = dinv[r] * ew[i] * dinv[c];
    }
}

// ---------------------------------------------------------------------------
// XCD-sliced aggregation over PACKED fp16 activations (uint2 = 4 feats/lane):
//   acc[n,f] = dinv[n]^2 * x[n,f] + sum_in w * x[src,f]   (fp32 accumulate)
// One 64-thr block per (node, 128-feat slice); lane owns one uint2 (8B) ->
// 512B/wave gathers (coalescing sweet spot), half the waves + half the CSR
// scalar reads vs the 4B/lane version.  node = blockIdx>>shift is UNIFORM ->
// CSR metadata scalarized (s_load_dwordx4), gather bases in SGPRs.
// [R1 lesson: keep 64-thr blocks; no launch_bounds min-wave clamp]
// Slab per slice = 10000 x 128 x 2B = 2.56 MB < 4 MB per-XCD L2.
// ---------------------------------------------------------------------------
template <int F, int SSHIFT>
__global__ __launch_bounds__(64) void agg_slice_kernel(const uint2* __restrict__ xpk,
                                                       const int* __restrict__ ptr,
                                                       const int* __restrict__ csr_src,
                                                       const float* __restrict__ csr_w,
                                                       const float* __restrict__ dinv,
                                                       uint2* __restrict__ o) {
    constexpr int F4 = F / 4;                     // uint2 units per row
    const int b = blockIdx.x;
    const int slice = b & ((1 << SSHIFT) - 1);
    const int node = b >> SSHIFT;                 // uniform
    const int q = slice * 64 + (int)threadIdx.x;  // uint2 index within row
    const float di = dinv[node];
    const float si = di * di;
    uint2 gs = xpk[node * F4 + q];
    float acc0 = si * h2f_lo(gs.x);
    float acc1 = si * h2f_hi(gs.x);
    float acc2 = si * h2f_lo(gs.y);
    float acc3 = si * h2f_hi(gs.y);
    const int s = ptr[node], e = ptr[node + 1];   // 8-aligned, length % 8 == 0

    for (int j = s; j < e; j += 8) {
        // uniform indices -> s_load_dwordx4; weights land in SGPRs
        int4   sa = *(const int4*)(csr_src + j);
        int4   sb = *(const int4*)(csr_src + j + 4);
        float4 wa = *(const float4*)(csr_w + j);
        float4 wb = *(const float4*)(csr_w + j + 4);
        // 8 independent 8B gathers in flight (scalar bases)
        uint2 g0 = xpk[sa.x * F4 + q];
        uint2 g1 = xpk[sa.y * F4 + q];
        uint2 g2 = xpk[sa.z * F4 + q];
        uint2 g3 = xpk[sa.w * F4 + q];
        uint2 g4 = xpk[sb.x * F4 + q];
        uint2 g5 = xpk[sb.y * F4 + q];
        uint2 g6 = xpk[sb.z * F4 + q];
        uint2 g7 = xpk[sb.w * F4 + q];
        acc0 += wa.x * h2f_lo(g0.x) + wa.y * h2f_lo(g1.x) + wa.z * h2f_lo(g2.x) + wa.w * h2f_lo(g3.x);
        acc1 += wa.x * h2f_hi(g0.x) + wa.y * h2f_hi(g1.x) + wa.z * h2f_hi(g2.x) + wa.w * h2f_hi(g3.x);
        acc2 += wa.x * h2f_lo(g0.y) + wa.y * h2f_lo(g1.y) + wa.z * h2f_lo(g2.y) + wa.w * h2f_lo(g3.y);
        acc3 += wa.x * h2f_hi(g0.y) + wa.y * h2f_hi(g1.y) + wa.z * h2f_hi(g2.y) + wa.w * h2f_hi(g3.y);
        acc0 += wb.x * h2f_lo(g4.x) + wb.y * h2f_lo(g5.x) + wb.z * h2f_lo(g6.x) + wb.w * h2f_lo(g7.x);
        acc1 += wb.x * h2f_hi(g4.x) + wb.y * h2f_hi(g5.x) + wb.z * h2f_hi(g6.x) + wb.w * h2f_hi(g7.x);
        acc2 += wb.x * h2f_lo(g4.y) + wb.y * h2f_lo(g5.y) + wb.z * h2f_lo(g6.y) + wb.w * h2f_lo(g7.y);
        acc3 += wb.x * h2f_hi(g4.y) + wb.y * h2f_hi(g5.y) + wb.z * h2f_hi(g6.y) + wb.w * h2f_hi(g7.y);
    }

    uint2 r;
    r.x = ((unsigned int)f2h_bits(acc1) << 16) | f2h_bits(acc0);
    r.y = ((unsigned int)f2h_bits(acc3) << 16) | f2h_bits(acc2);
    o[node * F4 + q] = r;
}

// ---------------------------------------------------------------------------
// fp16 MFMA GEMM + bias + relu, async global->LDS staging, fp16 output.
//   C[M,N] = A[M,K] @ B[K,N] + bias   (fp32 accumulate, single pass)
// B transposed as Bt[N][K]; A row-padded to TM multiple (pad rows discarded).
// Tile 128m x 128n, BK=32, 256 threads = 4 waves of 64m x 64n.
// LDS 16KB/buf x 2 = 32KB -> 3 blocks/CU.
// ---------------------------------------------------------------------------
typedef _Float16 half8 __attribute__((ext_vector_type(8)));
typedef float f32x4 __attribute__((ext_vector_type(4)));

#define TM 128
#define TN 128
#define BK 32
#define LDS_A 0
#define LDS_B 8192
#define LDS_BUF 16384

__device__ __forceinline__ void async16(const unsigned short* g, unsigned char* l) {
    __builtin_amdgcn_global_load_lds(
        (const __attribute__((address_space(1))) unsigned int*)g,
        (__attribute__((address_space(3))) unsigned int*)l, 16, 0, 0);
}

__global__ __launch_bounds__(256, 3) void gemm_mfma_kernel(
        const unsigned short* __restrict__ A,
        const unsigned short* __restrict__ Bt,
        const float* __restrict__ bias,
        unsigned short* __restrict__ Cb,
        int M, int K, int N) {
    __shared__ unsigned char lds[2 * LDS_BUF];
    const int t = (int)threadIdx.x;

    // bijective XCD-chunked remap (m204): same-row-panel tiles share an XCD L2
    const int gx = (int)gridDim.x;
    const int nwg = gx * (int)gridDim.y;
    const int lin = (int)blockIdx.y * gx + (int)blockIdx.x;
    const int xcd = lin & 7, idx = lin >> 3;
    const int q = nwg >> 3, r = nwg & 7;
    const int logi = (xcd < r ? xcd * (q + 1) : r * (q + 1) + (xcd - r) * q) + idx;
    const int bm = (logi / gx) * TM;
    const int bn = (logi % gx) * TN;

    const int lane = t & 63;
    const int wave = t >> 6;
    const int wm = (wave & 1) * 64;
    const int wn = (wave >> 1) * 64;

    // ---- staging geometry (per lane): 16-row blocks, 1024 B per async issue ----
    const int slr = lane >> 2;                       // 0..15 local row
    const int scc = (lane & 3) ^ ((slr >> 1) & 3);   // swizzled global chunk
    const int bi0 = wave * 2, bi1 = wave * 2 + 1;    // 16-row block ids (0..7)
    const unsigned short* gA0 = A + (size_t)(bm + bi0 * 16 + slr) * K + scc * 8;
    const unsigned short* gA1 = A + (size_t)(bm + bi1 * 16 + slr) * K + scc * 8;
    const unsigned short* gB0 = Bt + (size_t)(bn + bi0 * 16 + slr) * K + scc * 8;
    const unsigned short* gB1 = Bt + (size_t)(bn + bi1 * 16 + slr) * K + scc * 8;

    // ---- fragment read geometry ----
    const int quad = lane >> 4;
    const int lr16 = lane & 15;
    const int fs = (quad ^ ((lr16 >> 1) & 3)) * 16;  // swizzled slot byte offset

    f32x4 acc[4][4];
    const f32x4 zero4 = {0.f, 0.f, 0.f, 0.f};
#pragma unroll
    for (int i = 0; i < 4; ++i)
#pragma unroll
        for (int j = 0; j < 4; ++j) acc[i][j] = zero4;

    const int KT = K / BK;

    auto stage = [&](int kt, int buf) {
        const int k0 = kt * BK;
        unsigned char* b = &lds[buf * LDS_BUF];
        async16(gA0 + k0, b + LDS_A + bi0 * 1024);
        async16(gA1 + k0, b + LDS_A + bi1 * 1024);
        async16(gB0 + k0, b + LDS_B + bi0 * 1024);
        async16(gB1 + k0, b + LDS_B + bi1 * 1024);
    };

    stage(0, 0);
    __syncthreads();

    for (int kt = 0; kt < KT; ++kt) {
        const int buf = kt & 1;
        if (kt + 1 < KT) stage(kt + 1, buf ^ 1);   // async, drains at barrier below

        unsigned char* b = &lds[buf * LDS_BUF];
        half8 av[4], bv[4];
#pragma unroll
        for (int i = 0; i < 4; ++i) {
            int ro = (wm + i * 16 + lr16) * 64 + fs;
            av[i] = *(const half8*)(b + LDS_A + ro);
        }
#pragma unroll
        for (int j = 0; j < 4; ++j) {
            int ro = (wn + j * 16 + lr16) * 64 + fs;
            bv[j] = *(const half8*)(b + LDS_B + ro);
        }
#pragma unroll
        for (int i = 0; i < 4; ++i)
#pragma unroll
            for (int j = 0; j < 4; ++j)
                acc[i][j] = __builtin_amdgcn_mfma_f32_16x16x32_f16(av[i], bv[j], acc[i][j], 0, 0, 0);
        __syncthreads();
    }

    // epilogue: bias + relu, store fp16
    float bcol[4];
#pragma unroll
    for (int j = 0; j < 4; ++j) bcol[j] = bias[bn + wn + j * 16 + lr16];
#pragma unroll
    for (int i = 0; i < 4; ++i) {
#pragma unroll
        for (int r2 = 0; r2 < 4; ++r2) {
            int m = bm + wm + i * 16 + quad * 4 + r2;
            if (m < M) {
#pragma unroll
                for (int j = 0; j < 4; ++j) {
                    float vv = fmaxf(acc[i][j][r2] + bcol[j], 0.f);
                    Cb[(size_t)m * N + bn + wn + j * 16 + lr16] = f2h_bits(vv);
                }
            }
        }
    }
}

// ---------------------------------------------------------------------------
// GEMM for layer 3: N=8, K=768, A packed fp16 pairs.  One wave per row.
// ---------------------------------------------------------------------------
__global__ __launch_bounds__(64) void gemm_n8_kernel(const unsigned int* __restrict__ Apk,
                                                     const float* __restrict__ B,
                                                     float* __restrict__ C) {
    const int m = blockIdx.x;
    const int lane = (int)threadIdx.x;
    const unsigned int* a = Apk + m * 384;   // 384 pairs = 768 feats
    float acc[8] = {};
#pragma unroll
    for (int it = 0; it < 6; ++it) {
        int j2 = lane + it * 64;
        unsigned int av = a[j2];
        float a0 = h2f_lo(av), a1 = h2f_hi(av);
        const float* B0 = B + (size_t)(2 * j2) * 8;
        float4 p0 = *(const float4*)(B0);
        float4 p1 = *(const float4*)(B0 + 4);
        float4 q0 = *(const float4*)(B0 + 8);
        float4 q1 = *(const float4*)(B0 + 12);
        acc[0] += a0 * p0.x + a1 * q0.x; acc[1] += a0 * p0.y + a1 * q0.y;
        acc[2] += a0 * p0.z + a1 * q0.z; acc[3] += a0 * p0.w + a1 * q0.w;
        acc[4] += a0 * p1.x + a1 * q1.x; acc[5] += a0 * p1.y + a1 * q1.y;
        acc[6] += a0 * p1.z + a1 * q1.z; acc[7] += a0 * p1.w + a1 * q1.w;
    }
#pragma unroll
    for (int off = 32; off > 0; off >>= 1) {
#pragma unroll
        for (int i = 0; i < 8; ++i) acc[i] += __shfl_down(acc[i], off);
    }
    if (lane == 0) {
#pragma unroll
        for (int i = 0; i < 8; ++i) C[(size_t)m * 8 + i] = acc[i];
    }
}

// Aggregation for fout=8 (final layer, +bias): one wave per node, lanes split edges.
__global__ __launch_bounds__(64) void agg8_kernel(const float* __restrict__ xw,
                                                  const int* __restrict__ ptr,
                                                  const int* __restrict__ csr_src,
                                                  const float* __restrict__ csr_w,
                                                  const float* __restrict__ dinv,
                                                  const float* __restrict__ bias,
                                                  float* __restrict__ out) {
    int node = blockIdx.x;
    int lane = threadIdx.x;
    float acc[8] = {};
    int s = ptr[node], e = ptr[node + 1];
    for (int j = s + lane; j < e; j += 64) {
        int src = csr_src[j];
        float w = csr_w[j];
        float4 g0 = *(const float4*)(xw + (size_t)src * 8);
        float4 g1 = *(const float4*)(xw + (size_t)src * 8 + 4);
        acc[0] += w * g0.x; acc[1] += w * g0.y; acc[2] += w * g0.z; acc[3] += w * g0.w;
        acc[4] += w * g1.x; acc[5] += w * g1.y; acc[6] += w * g1.z; acc[7] += w * g1.w;
    }
#pragma unroll
    for (int off = 32; off > 0; off >>= 1) {
#pragma unroll
        for (int i = 0; i < 8; ++i) acc[i] += __shfl_down(acc[i], off);
    }
    if (lane == 0) {
        float di = dinv[node];
        float si = di * di;
#pragma unroll
        for (int i = 0; i < 8; ++i)
            out[(size_t)node * 8 + i] = acc[i] + si * xw[(size_t)node * 8 + i] + bias[i];
    }
}

// ---------------------------------------------------------------------------

extern "C" void kernel_launch(void* const* d_in, const int* in_sizes, int n_in,
                              void* d_out, int out_size, void* d_ws, size_t ws_size,
                              hipStream_t stream) {
    const int N = N_NODES, E = N_EDGES;
    const int N_PAD = ((N + TM - 1) / TM) * TM;   // 10112
    const float* x   = (const float*)d_in[0];
    const int*   ei  = (const int*)d_in[1];   // [2, E] (row=source, col=target)
    const float* ew  = (const float*)d_in[2];
    const float* W1  = (const float*)d_in[3];
    const float* b1  = (const float*)d_in[4];
    const float* W2  = (const float*)d_in[5];
    const float* b2  = (const float*)d_in[6];
    const float* W3  = (const float*)d_in[7];
    const float* b3  = (const float*)d_in[8];
    float* out = (float*)d_out;

    const int* row = ei;        // source
    const int* col = ei + E;    // target

    // workspace layout (256B-aligned); ~46 MB total
    char* ws = (char*)d_ws;
    size_t off = 0;
    auto alloc = [&](size_t bytes) {
        void* p = ws + off;
        off += (bytes + 255) & ~(size_t)255;
        return p;
    };
    float*          deg     = (float*)alloc((size_t)N * 4);
    float*          dinv    = (float*)alloc((size_t)N * 4);
    int*            counts  = (int*)alloc((size_t)N * 4);
    int*            col_ptr = (int*)alloc((size_t)(N + 1) * 4);
    int*            csr_src = (int*)alloc((size_t)E_PAD * 4);
    float*          csr_w   = (float*)alloc((size_t)E_PAD * 4);
    unsigned short* xh      = (unsigned short*)alloc((size_t)N * 256 * 2);   // x as fp16
    unsigned short* h1h     = (unsigned short*)alloc((size_t)N * 512 * 2);   // gemm1 out fp16
    unsigned short* h2h     = (unsigned short*)alloc((size_t)N * 768 * 2);   // gemm2 out fp16
    unsigned short* Aagg    = (unsigned short*)alloc((size_t)N_PAD * 512 * 2); // agg out (both layers)
    unsigned short* W1t     = (unsigned short*)alloc((size_t)512 * 256 * 2);
    unsigned short* W2t     = (unsigned short*)alloc((size_t)768 * 512 * 2);
    float*          xw8     = (float*)alloc((size_t)N * 8 * 4);
    (void)ws_size;

    int nb_edges = (E + 255) / 256;

    // --- fused setup (init + CSR zero + x->fp16 + weight conversion) ---
    {
        int tot = N + E_PAD + N * 256 + 256 * 512 + 512 * 768;
        setup_kernel<<<(tot + 255) / 256, 256, 0, stream>>>(
            deg, counts, csr_src, csr_w, x, xh, W1, W1t, W2, W2t);
    }
    count_kernel<<<nb_edges, 256, 0, stream>>>(col, ew, deg, counts, E);
    scan_dinv_kernel<<<1, 1024, 0, stream>>>(counts, col_ptr, deg, dinv, N);
    scatter_kernel<<<nb_edges, 256, 0, stream>>>(row, col, ew, dinv, col_ptr, counts,
                                                 csr_src, csr_w, E);

    // --- layer 1: agg(fp16 x, 1 slice of 128 pairs) -> gemm 256->512 (+b1, relu)
    agg_slice_kernel<256, 0><<<N, 64, 0, stream>>>(
        (const uint2*)xh, col_ptr, csr_src, csr_w, dinv, (uint2*)Aagg);
    {
        dim3 grid(512 / TN, N_PAD / TM);
        gemm_mfma_kernel<<<grid, 256, 0, stream>>>(Aagg, W1t, b1, h1h, N, 256, 512);
    }
    // --- layer 2: agg(fp16 h1, 2 slices) -> gemm 512->768 (+b2, relu)
    agg_slice_kernel<512, 1><<<N * 2, 64, 0, stream>>>(
        (const uint2*)h1h, col_ptr, csr_src, csr_w, dinv, (uint2*)Aagg);
    {
        dim3 grid(768 / TN, N_PAD / TM);
        gemm_mfma_kernel<<<grid, 256, 0, stream>>>(Aagg, W2t, b2, h2h, N, 512, 768);
    }
    // --- layer 3: gemm 768->8 (packed fp16 A) -> agg8 (+b3) ---
    gemm_n8_kernel<<<N, 64, 0, stream>>>((const unsigned int*)h2h, W3, xw8);
    agg8_kernel<<<N, 64, 0, stream>>>(xw8, col_ptr, csr_src, csr_w, dinv, b3, out);

    (void)out_size; (void)n_in; (void)in_sizes;
}

// Round 4
// 242.122 us; speedup vs baseline: 1.0474x; 1.0287x over previous
//
#include <hip/hip_runtime.h>

#define N_NODES 10000
#define N_EDGES 320000
#define E_PAD (N_EDGES + 8 * N_NODES)   // CSR padded to 8-multiples per node

// ---------------------------------------------------------------------------
// fp16 helpers (RNE via v_cvt_f16_f32 / v_cvt_f32_f16)
// ---------------------------------------------------------------------------
__device__ __forceinline__ unsigned short f2h_bits(float v) {
    _Float16 h = (_Float16)v;
    unsigned short u;
    __builtin_memcpy(&u, &h, 2);
    return u;
}
// packed-pair unpack: u32 holds fp16 features (2j, 2j+1) little-endian
__device__ __forceinline__ float h2f_lo(unsigned int g) {
    unsigned short u = (unsigned short)(g & 0xFFFFu);
    _Float16 h; __builtin_memcpy(&h, &u, 2);
    return (float)h;
}
__device__ __forceinline__ float h2f_hi(unsigned int g) {
    unsigned short u = (unsigned short)(g >> 16);
    _Float16 h; __builtin_memcpy(&h, &u, 2);
    return (float)h;
}

// ---------------------------------------------------------------------------
// Fused setup: deg/counts init + CSR zero + x->fp16 + W1/W2 fp16 transpose.
// ---------------------------------------------------------------------------
__global__ __launch_bounds__(256) void setup_kernel(
        float* __restrict__ deg, int* __restrict__ counts,
        int* __restrict__ csr_src, float* __restrict__ csr_w,
        const float* __restrict__ x, unsigned short* __restrict__ xh,
        const float* __restrict__ W1, unsigned short* __restrict__ w1t,
        const float* __restrict__ W2, unsigned short* __restrict__ w2t) {
    int i = blockIdx.x * 256 + threadIdx.x;
    const int S0 = N_NODES;                  // deg/counts
    const int S1 = S0 + E_PAD;               // csr zero
    const int S2 = S1 + N_NODES * 256;       // x -> fp16
    const int S3 = S2 + 256 * 512;           // W1
    const int S4 = S3 + 512 * 768;           // W2
    if (i < S0) {
        deg[i] = 1.0f; counts[i] = 0;        // self-loop weight 1
    } else if (i < S1) {
        int j = i - S0;
        csr_src[j] = 0; csr_w[j] = 0.f;      // pad edges: node 0, weight 0
    } else if (i < S2) {
        int j = i - S1;
        xh[j] = f2h_bits(x[j]);
    } else if (i < S3) {
        int j = i - S2;
        int k = j >> 9, n = j & 511;         // W1 [256][512]
        w1t[n * 256 + k] = f2h_bits(W1[j]);
    } else if (i < S4) {
        int j = i - S3;
        int k = j / 768, n = j - k * 768;    // W2 [512][768]
        w2t[n * 512 + k] = f2h_bits(W2[j]);
    }
}

// Degree + count with slot recording: slot[i] = this edge's rank within its
// destination segment -> scatter needs no atomics.  [R1/R2 lesson: keep slot]
__global__ __launch_bounds__(256) void count_slot_kernel(const int* __restrict__ col,
                                                         const float* __restrict__ ew,
                                                         float* __restrict__ deg,
                                                         int* __restrict__ counts,
                                                         int* __restrict__ slot, int e) {
    int i = blockIdx.x * 256 + threadIdx.x;
    if (i < e) {
        int c = col[i];
        slot[i] = atomicAdd(counts + c, 1);
        atomicAdd(deg + c, ew[i]);
    }
}

// Single-block scan, 2 barriers: each thread owns 10 contiguous counts
// (local serial prefix), then wave-scan + 16-partial block scan.
// Emits 8-padded exclusive ptr + fused dinv.
__global__ __launch_bounds__(1024) void scan_dinv_kernel(const int* __restrict__ counts,
                                                         int* __restrict__ ptr,
                                                         const float* __restrict__ deg,
                                                         float* __restrict__ dinv, int n) {
    __shared__ int wsum[16];
    __shared__ int woff[16];
    const int t = (int)threadIdx.x;
    const int lane = t & 63;
    const int wid = t >> 6;
    const int base = t * 10;
    int loc[10];
    int tot = 0;
#pragma unroll
    for (int q = 0; q < 10; ++q) {
        int i = base + q;
        int v = 0;
        if (i < n) {
            v = (counts[i] + 7) & ~7;        // pad to multiple of 8
            float d = deg[i];
            dinv[i] = (d > 0.0f) ? rsqrtf(d) : 0.0f;
        }
        loc[q] = tot;                        // exclusive local prefix
        tot += v;
    }
    int x = tot;                             // wave-inclusive scan of totals
#pragma unroll
    for (int off = 1; off < 64; off <<= 1) {
        int u = __shfl_up(x, off);
        if (lane >= off) x += u;
    }
    if (lane == 63) wsum[wid] = x;
    __syncthreads();                         // B1
    if (wid == 0 && lane < 16) {
        int s = wsum[lane];
        int y = s;
#pragma unroll
        for (int off = 1; off < 16; off <<= 1) {
            int u = __shfl_up(y, off);
            if (lane >= off) y += u;
        }
        woff[lane] = y - s;                  // exclusive wave offsets
        if (lane == 15) ptr[n] = y;          // grand total
    }
    __syncthreads();                         // B2
    const int tbase = woff[wid] + (x - tot); // thread's exclusive offset
#pragma unroll
    for (int q = 0; q < 10; ++q) {
        int i = base + q;
        if (i < n) ptr[i] = tbase + loc[q];
    }
}

// Scatter without atomics: pos = ptr[col] + precomputed slot.
__global__ __launch_bounds__(256) void scatter_kernel(const int* __restrict__ row,
                                                      const int* __restrict__ col,
                                                      const float* __restrict__ ew,
                                                      const float* __restrict__ dinv,
                                                      const int* __restrict__ ptr,
                                                      const int* __restrict__ slot,
                                                      int* __restrict__ csr_src,
                                                      float* __restrict__ csr_w, int e) {
    int i = blockIdx.x * 256 + threadIdx.x;
    if (i < e) {
        int c = col[i], r = row[i];
        int pos = ptr[c] + slot[i];
        csr_src[pos] = r;
        csr_w[pos] = dinv[r] * ew[i] * dinv[c];
    }
}

// ---------------------------------------------------------------------------
// XCD-sliced aggregation over PACKED fp16 activations, fp16 output:
//   acc[n,f] = dinv[n]^2 * x[n,f] + sum_in w * x[src,f]   (fp32 accumulate)
// One WAVE per (node, 64-PAIR slice = 128 features); lane = one u32 pair.
// Slab per slice = 10000 x 128 x 2B = 2.56 MB < 4 MB per-XCD L2.  [R2 lesson:
// keep slices at 128 feats]
// 4 wave-units per 256-thr block (64-thr blocks cap at 16 wg/CU = 16 waves/CU;
// this reaches 32 waves/CU).  NO min-occupancy clamp (R1 lesson: the (256,8)
// clamp forces <=64 VGPR and breaks the gather unroll).
// node via readfirstlane -> scalar CSR metadata, gather bases in SGPRs.
// ---------------------------------------------------------------------------
template <int F, int SSHIFT>
__global__ __launch_bounds__(256) void agg_slice_kernel(const unsigned int* __restrict__ xpk,
                                                        const int* __restrict__ ptr,
                                                        const int* __restrict__ csr_src,
                                                        const float* __restrict__ csr_w,
                                                        const float* __restrict__ dinv,
                                                        unsigned int* __restrict__ o) {
    constexpr int F2 = F / 2;
    const int unit = __builtin_amdgcn_readfirstlane(
        (int)blockIdx.x * 4 + ((int)threadIdx.x >> 6));
    const int slice = unit & ((1 << SSHIFT) - 1);
    const int node = unit >> SSHIFT;              // scalar
    const int lane = (int)threadIdx.x & 63;
    const int f2 = slice * 64 + lane;             // pair index
    const float di = dinv[node];
    const float si = di * di;
    unsigned int gs = xpk[node * F2 + f2];
    float acc0 = si * h2f_lo(gs);
    float acc1 = si * h2f_hi(gs);
    const int s = ptr[node], e = ptr[node + 1];   // 8-aligned, length % 8 == 0

    for (int j = s; j < e; j += 8) {
        // uniform indices -> s_load_dwordx4; weights land in SGPRs
        int4   sa = *(const int4*)(csr_src + j);
        int4   sb = *(const int4*)(csr_src + j + 4);
        float4 wa = *(const float4*)(csr_w + j);
        float4 wb = *(const float4*)(csr_w + j + 4);
        // 8 independent dword gathers in flight (scalar bases)
        unsigned int g0 = xpk[sa.x * F2 + f2];
        unsigned int g1 = xpk[sa.y * F2 + f2];
        unsigned int g2 = xpk[sa.z * F2 + f2];
        unsigned int g3 = xpk[sa.w * F2 + f2];
        unsigned int g4 = xpk[sb.x * F2 + f2];
        unsigned int g5 = xpk[sb.y * F2 + f2];
        unsigned int g6 = xpk[sb.z * F2 + f2];
        unsigned int g7 = xpk[sb.w * F2 + f2];
        acc0 += wa.x * h2f_lo(g0) + wa.y * h2f_lo(g1) + wa.z * h2f_lo(g2) + wa.w * h2f_lo(g3);
        acc1 += wa.x * h2f_hi(g0) + wa.y * h2f_hi(g1) + wa.z * h2f_hi(g2) + wa.w * h2f_hi(g3);
        acc0 += wb.x * h2f_lo(g4) + wb.y * h2f_lo(g5) + wb.z * h2f_lo(g6) + wb.w * h2f_lo(g7);
        acc1 += wb.x * h2f_hi(g4) + wb.y * h2f_hi(g5) + wb.z * h2f_hi(g6) + wb.w * h2f_hi(g7);
    }

    unsigned short h0 = f2h_bits(acc0);
    unsigned short h1 = f2h_bits(acc1);
    o[node * F2 + f2] = ((unsigned int)h1 << 16) | h0;
}

// ---------------------------------------------------------------------------
// fp16 MFMA GEMM + bias + relu, async global->LDS staging, fp16 output.
//   C[M,N] = A[M,K] @ B[K,N] + bias   (fp32 accumulate, single pass)
// B transposed as Bt[N][K]; A row-padded to TM multiple (pad rows discarded).
// Tile 128m x 128n, BK=32, 256 threads = 4 waves of 64m x 64n.
// LDS 16KB/buf x 2 = 32KB -> 3 blocks/CU.
// ---------------------------------------------------------------------------
typedef _Float16 half8 __attribute__((ext_vector_type(8)));
typedef float f32x4 __attribute__((ext_vector_type(4)));

#define TM 128
#define TN 128
#define BK 32
#define LDS_A 0
#define LDS_B 8192
#define LDS_BUF 16384

__device__ __forceinline__ void async16(const unsigned short* g, unsigned char* l) {
    __builtin_amdgcn_global_load_lds(
        (const __attribute__((address_space(1))) unsigned int*)g,
        (__attribute__((address_space(3))) unsigned int*)l, 16, 0, 0);
}

__global__ __launch_bounds__(256, 3) void gemm_mfma_kernel(
        const unsigned short* __restrict__ A,
        const unsigned short* __restrict__ Bt,
        const float* __restrict__ bias,
        unsigned short* __restrict__ Cb,
        int M, int K, int N) {
    __shared__ unsigned char lds[2 * LDS_BUF];
    const int t = (int)threadIdx.x;

    // bijective XCD-chunked remap (m204): same-row-panel tiles share an XCD L2
    const int gx = (int)gridDim.x;
    const int nwg = gx * (int)gridDim.y;
    const int lin = (int)blockIdx.y * gx + (int)blockIdx.x;
    const int xcd = lin & 7, idx = lin >> 3;
    const int q = nwg >> 3, r = nwg & 7;
    const int logi = (xcd < r ? xcd * (q + 1) : r * (q + 1) + (xcd - r) * q) + idx;
    const int bm = (logi / gx) * TM;
    const int bn = (logi % gx) * TN;

    const int lane = t & 63;
    const int wave = t >> 6;
    const int wm = (wave & 1) * 64;
    const int wn = (wave >> 1) * 64;

    // ---- staging geometry (per lane): 16-row blocks, 1024 B per async issue ----
    const int slr = lane >> 2;                       // 0..15 local row
    const int scc = (lane & 3) ^ ((slr >> 1) & 3);   // swizzled global chunk
    const int bi0 = wave * 2, bi1 = wave * 2 + 1;    // 16-row block ids (0..7)
    const unsigned short* gA0 = A + (size_t)(bm + bi0 * 16 + slr) * K + scc * 8;
    const unsigned short* gA1 = A + (size_t)(bm + bi1 * 16 + slr) * K + scc * 8;
    const unsigned short* gB0 = Bt + (size_t)(bn + bi0 * 16 + slr) * K + scc * 8;
    const unsigned short* gB1 = Bt + (size_t)(bn + bi1 * 16 + slr) * K + scc * 8;

    // ---- fragment read geometry ----
    const int quad = lane >> 4;
    const int lr16 = lane & 15;
    const int fs = (quad ^ ((lr16 >> 1) & 3)) * 16;  // swizzled slot byte offset

    f32x4 acc[4][4];
    const f32x4 zero4 = {0.f, 0.f, 0.f, 0.f};
#pragma unroll
    for (int i = 0; i < 4; ++i)
#pragma unroll
        for (int j = 0; j < 4; ++j) acc[i][j] = zero4;

    const int KT = K / BK;

    auto stage = [&](int kt, int buf) {
        const int k0 = kt * BK;
        unsigned char* b = &lds[buf * LDS_BUF];
        async16(gA0 + k0, b + LDS_A + bi0 * 1024);
        async16(gA1 + k0, b + LDS_A + bi1 * 1024);
        async16(gB0 + k0, b + LDS_B + bi0 * 1024);
        async16(gB1 + k0, b + LDS_B + bi1 * 1024);
    };

    stage(0, 0);
    __syncthreads();

    for (int kt = 0; kt < KT; ++kt) {
        const int buf = kt & 1;
        if (kt + 1 < KT) stage(kt + 1, buf ^ 1);   // async, drains at barrier below

        unsigned char* b = &lds[buf * LDS_BUF];
        half8 av[4], bv[4];
#pragma unroll
        for (int i = 0; i < 4; ++i) {
            int ro = (wm + i * 16 + lr16) * 64 + fs;
            av[i] = *(const half8*)(b + LDS_A + ro);
        }
#pragma unroll
        for (int j = 0; j < 4; ++j) {
            int ro = (wn + j * 16 + lr16) * 64 + fs;
            bv[j] = *(const half8*)(b + LDS_B + ro);
        }
#pragma unroll
        for (int i = 0; i < 4; ++i)
#pragma unroll
            for (int j = 0; j < 4; ++j)
                acc[i][j] = __builtin_amdgcn_mfma_f32_16x16x32_f16(av[i], bv[j], acc[i][j], 0, 0, 0);
        __syncthreads();
    }

    // epilogue: bias + relu, store fp16
    float bcol[4];
#pragma unroll
    for (int j = 0; j < 4; ++j) bcol[j] = bias[bn + wn + j * 16 + lr16];
#pragma unroll
    for (int i = 0; i < 4; ++i) {
#pragma unroll
        for (int r2 = 0; r2 < 4; ++r2) {
            int m = bm + wm + i * 16 + quad * 4 + r2;
            if (m < M) {
#pragma unroll
                for (int j = 0; j < 4; ++j) {
                    float vv = fmaxf(acc[i][j][r2] + bcol[j], 0.f);
                    Cb[(size_t)m * N + bn + wn + j * 16 + lr16] = f2h_bits(vv);
                }
            }
        }
    }
}

// ---------------------------------------------------------------------------
// GEMM for layer 3: N=8, K=768, A packed fp16 pairs.  One wave per row.
// ---------------------------------------------------------------------------
__global__ __launch_bounds__(64) void gemm_n8_kernel(const unsigned int* __restrict__ Apk,
                                                     const float* __restrict__ B,
                                                     float* __restrict__ C) {
    const int m = blockIdx.x;
    const int lane = (int)threadIdx.x;
    const unsigned int* a = Apk + m * 384;   // 384 pairs = 768 feats
    float acc[8] = {};
#pragma unroll
    for (int it = 0; it < 6; ++it) {
        int j2 = lane + it * 64;
        unsigned int av = a[j2];
        float a0 = h2f_lo(av), a1 = h2f_hi(av);
        const float* B0 = B + (size_t)(2 * j2) * 8;
        float4 p0 = *(const float4*)(B0);
        float4 p1 = *(const float4*)(B0 + 4);
        float4 q0 = *(const float4*)(B0 + 8);
        float4 q1 = *(const float4*)(B0 + 12);
        acc[0] += a0 * p0.x + a1 * q0.x; acc[1] += a0 * p0.y + a1 * q0.y;
        acc[2] += a0 * p0.z + a1 * q0.z; acc[3] += a0 * p0.w + a1 * q0.w;
        acc[4] += a0 * p1.x + a1 * q1.x; acc[5] += a0 * p1.y + a1 * q1.y;
        acc[6] += a0 * p1.z + a1 * q1.z; acc[7] += a0 * p1.w + a1 * q1.w;
    }
#pragma unroll
    for (int off = 32; off > 0; off >>= 1) {
#pragma unroll
        for (int i = 0; i < 8; ++i) acc[i] += __shfl_down(acc[i], off);
    }
    if (lane == 0) {
#pragma unroll
        for (int i = 0; i < 8; ++i) C[(size_t)m * 8 + i] = acc[i];
    }
}

// Aggregation for fout=8 (final layer, +bias): one wave per node, lanes split edges.
__global__ __launch_bounds__(64) void agg8_kernel(const float* __restrict__ xw,
                                                  const int* __restrict__ ptr,
                                                  const int* __restrict__ csr_src,
                                                  const float* __restrict__ csr_w,
                                                  const float* __restrict__ dinv,
                                                  const float* __restrict__ bias,
                                                  float* __restrict__ out) {
    int node = blockIdx.x;
    int lane = threadIdx.x;
    float acc[8] = {};
    int s = ptr[node], e = ptr[node + 1];
    for (int j = s + lane; j < e; j += 64) {
        int src = csr_src[j];
        float w = csr_w[j];
        float4 g0 = *(const float4*)(xw + (size_t)src * 8);
        float4 g1 = *(const float4*)(xw + (size_t)src * 8 + 4);
        acc[0] += w * g0.x; acc[1] += w * g0.y; acc[2] += w * g0.z; acc[3] += w * g0.w;
        acc[4] += w * g1.x; acc[5] += w * g1.y; acc[6] += w * g1.z; acc[7] += w * g1.w;
    }
#pragma unroll
    for (int off = 32; off > 0; off >>= 1) {
#pragma unroll
        for (int i = 0; i < 8; ++i) acc[i] += __shfl_down(acc[i], off);
    }
    if (lane == 0) {
        float di = dinv[node];
        float si = di * di;
#pragma unroll
        for (int i = 0; i < 8; ++i)
            out[(size_t)node * 8 + i] = acc[i] + si * xw[(size_t)node * 8 + i] + bias[i];
    }
}

// ---------------------------------------------------------------------------

extern "C" void kernel_launch(void* const* d_in, const int* in_sizes, int n_in,
                              void* d_out, int out_size, void* d_ws, size_t ws_size,
                              hipStream_t stream) {
    const int N = N_NODES, E = N_EDGES;
    const int N_PAD = ((N + TM - 1) / TM) * TM;   // 10112
    const float* x   = (const float*)d_in[0];
    const int*   ei  = (const int*)d_in[1];   // [2, E] (row=source, col=target)
    const float* ew  = (const float*)d_in[2];
    const float* W1  = (const float*)d_in[3];
    const float* b1  = (const float*)d_in[4];
    const float* W2  = (const float*)d_in[5];
    const float* b2  = (const float*)d_in[6];
    const float* W3  = (const float*)d_in[7];
    const float* b3  = (const float*)d_in[8];
    float* out = (float*)d_out;

    const int* row = ei;        // source
    const int* col = ei + E;    // target

    // workspace layout (256B-aligned); ~47 MB total
    char* ws = (char*)d_ws;
    size_t off = 0;
    auto alloc = [&](size_t bytes) {
        void* p = ws + off;
        off += (bytes + 255) & ~(size_t)255;
        return p;
    };
    float*          deg     = (float*)alloc((size_t)N * 4);
    float*          dinv    = (float*)alloc((size_t)N * 4);
    int*            counts  = (int*)alloc((size_t)N * 4);
    int*            col_ptr = (int*)alloc((size_t)(N + 1) * 4);
    int*            slot    = (int*)alloc((size_t)E * 4);
    int*            csr_src = (int*)alloc((size_t)E_PAD * 4);
    float*          csr_w   = (float*)alloc((size_t)E_PAD * 4);
    unsigned short* xh      = (unsigned short*)alloc((size_t)N * 256 * 2);   // x as fp16
    unsigned short* h1h     = (unsigned short*)alloc((size_t)N * 512 * 2);   // gemm1 out fp16
    unsigned short* h2h     = (unsigned short*)alloc((size_t)N * 768 * 2);   // gemm2 out fp16
    unsigned short* Aagg    = (unsigned short*)alloc((size_t)N_PAD * 512 * 2); // agg out (both layers)
    unsigned short* W1t     = (unsigned short*)alloc((size_t)512 * 256 * 2);
    unsigned short* W2t     = (unsigned short*)alloc((size_t)768 * 512 * 2);
    float*          xw8     = (float*)alloc((size_t)N * 8 * 4);
    (void)ws_size;

    int nb_edges = (E + 255) / 256;

    // --- fused setup (init + CSR zero + x->fp16 + weight conversion) ---
    {
        int tot = N + E_PAD + N * 256 + 256 * 512 + 512 * 768;
        setup_kernel<<<(tot + 255) / 256, 256, 0, stream>>>(
            deg, counts, csr_src, csr_w, x, xh, W1, W1t, W2, W2t);
    }
    count_slot_kernel<<<nb_edges, 256, 0, stream>>>(col, ew, deg, counts, slot, E);
    scan_dinv_kernel<<<1, 1024, 0, stream>>>(counts, col_ptr, deg, dinv, N);
    scatter_kernel<<<nb_edges, 256, 0, stream>>>(row, col, ew, dinv, col_ptr, slot,
                                                 csr_src, csr_w, E);

    // --- layer 1: agg(fp16 x, 2 slices) -> gemm 256->512 (+b1, relu, fp16 out)
    agg_slice_kernel<256, 1><<<N * 2 / 4, 256, 0, stream>>>(
        (const unsigned int*)xh, col_ptr, csr_src, csr_w, dinv, (unsigned int*)Aagg);
    {
        dim3 grid(512 / TN, N_PAD / TM);
        gemm_mfma_kernel<<<grid, 256, 0, stream>>>(Aagg, W1t, b1, h1h, N, 256, 512);
    }
    // --- layer 2: agg(fp16 h1, 4 slices) -> gemm 512->768 (+b2, relu, fp16 out)
    agg_slice_kernel<512, 2><<<N * 4 / 4, 256, 0, stream>>>(
        (const unsigned int*)h1h, col_ptr, csr_src, csr_w, dinv, (unsigned int*)Aagg);
    {
        dim3 grid(768 / TN, N_PAD / TM);
        gemm_mfma_kernel<<<grid, 256, 0, stream>>>(Aagg, W2t, b2, h2h, N, 512, 768);
    }
    // --- layer 3: gemm 768->8 (packed fp16 A) -> agg8 (+b3) ---
    gemm_n8_kernel<<<N, 64, 0, stream>>>((const unsigned int*)h2h, W3, xw8);
    agg8_kernel<<<N, 64, 0, stream>>>(xw8, col_ptr, csr_src, csr_w, dinv, b3, out);

    (void)out_size; (void)n_in; (void)in_sizes;
}

// Round 5
// 229.834 us; speedup vs baseline: 1.1034x; 1.0535x over previous
//
#include <hip/hip_runtime.h>

#define N_NODES 10000
#define N_EDGES 320000
#define E_PAD (N_EDGES + 8 * N_NODES)   // CSR padded to 8-multiples per node

// ---------------------------------------------------------------------------
// fp16 helpers (RNE via v_cvt_f16_f32 / v_cvt_f32_f16)
// ---------------------------------------------------------------------------
__device__ __forceinline__ unsigned short f2h_bits(float v) {
    _Float16 h = (_Float16)v;
    unsigned short u;
    __builtin_memcpy(&u, &h, 2);
    return u;
}
// packed-pair unpack: u32 holds fp16 features (2j, 2j+1) little-endian
__device__ __forceinline__ float h2f_lo(unsigned int g) {
    unsigned short u = (unsigned short)(g & 0xFFFFu);
    _Float16 h; __builtin_memcpy(&h, &u, 2);
    return (float)h;
}
__device__ __forceinline__ float h2f_hi(unsigned int g) {
    unsigned short u = (unsigned short)(g >> 16);
    _Float16 h; __builtin_memcpy(&h, &u, 2);
    return (float)h;
}

// ---------------------------------------------------------------------------
// Fused setup: deg/counts init + CSR zero + x->fp16 + W1/W2 fp16 transpose.
// ---------------------------------------------------------------------------
__global__ __launch_bounds__(256) void setup_kernel(
        float* __restrict__ deg, int* __restrict__ counts,
        int* __restrict__ csr_src, float* __restrict__ csr_w,
        const float* __restrict__ x, unsigned short* __restrict__ xh,
        const float* __restrict__ W1, unsigned short* __restrict__ w1t,
        const float* __restrict__ W2, unsigned short* __restrict__ w2t) {
    int i = blockIdx.x * 256 + threadIdx.x;
    const int S0 = N_NODES;                  // deg/counts
    const int S1 = S0 + E_PAD;               // csr zero
    const int S2 = S1 + N_NODES * 256;       // x -> fp16
    const int S3 = S2 + 256 * 512;           // W1
    const int S4 = S3 + 512 * 768;           // W2
    if (i < S0) {
        deg[i] = 1.0f; counts[i] = 0;        // self-loop weight 1
    } else if (i < S1) {
        int j = i - S0;
        csr_src[j] = 0; csr_w[j] = 0.f;      // pad edges: node 0, weight 0
    } else if (i < S2) {
        int j = i - S1;
        xh[j] = f2h_bits(x[j]);
    } else if (i < S3) {
        int j = i - S2;
        int k = j >> 9, n = j & 511;         // W1 [256][512]
        w1t[n * 256 + k] = f2h_bits(W1[j]);
    } else if (i < S4) {
        int j = i - S3;
        int k = j / 768, n = j - k * 768;    // W2 [512][768]
        w2t[n * 512 + k] = f2h_bits(W2[j]);
    }
}

// Degree + count with slot recording: slot[i] = this edge's rank within its
// destination segment -> scatter needs no atomics.  [R1/R2 lesson: keep slot]
__global__ __launch_bounds__(256) void count_slot_kernel(const int* __restrict__ col,
                                                         const float* __restrict__ ew,
                                                         float* __restrict__ deg,
                                                         int* __restrict__ counts,
                                                         int* __restrict__ slot, int e) {
    int i = blockIdx.x * 256 + threadIdx.x;
    if (i < e) {
        int c = col[i];
        slot[i] = atomicAdd(counts + c, 1);
        atomicAdd(deg + c, ew[i]);
    }
}

// Single-block scan, 2 barriers: each thread owns 10 contiguous counts
// (local serial prefix), then wave-scan + 16-partial block scan.
// Emits 8-padded exclusive ptr + fused dinv.
__global__ __launch_bounds__(1024) void scan_dinv_kernel(const int* __restrict__ counts,
                                                         int* __restrict__ ptr,
                                                         const float* __restrict__ deg,
                                                         float* __restrict__ dinv, int n) {
    __shared__ int wsum[16];
    __shared__ int woff[16];
    const int t = (int)threadIdx.x;
    const int lane = t & 63;
    const int wid = t >> 6;
    const int base = t * 10;
    int loc[10];
    int tot = 0;
#pragma unroll
    for (int q = 0; q < 10; ++q) {
        int i = base + q;
        int v = 0;
        if (i < n) {
            v = (counts[i] + 7) & ~7;        // pad to multiple of 8
            float d = deg[i];
            dinv[i] = (d > 0.0f) ? rsqrtf(d) : 0.0f;
        }
        loc[q] = tot;                        // exclusive local prefix
        tot += v;
    }
    int x = tot;                             // wave-inclusive scan of totals
#pragma unroll
    for (int off = 1; off < 64; off <<= 1) {
        int u = __shfl_up(x, off);
        if (lane >= off) x += u;
    }
    if (lane == 63) wsum[wid] = x;
    __syncthreads();                         // B1
    if (wid == 0 && lane < 16) {
        int s = wsum[lane];
        int y = s;
#pragma unroll
        for (int off = 1; off < 16; off <<= 1) {
            int u = __shfl_up(y, off);
            if (lane >= off) y += u;
        }
        woff[lane] = y - s;                  // exclusive wave offsets
        if (lane == 15) ptr[n] = y;          // grand total
    }
    __syncthreads();                         // B2
    const int tbase = woff[wid] + (x - tot); // thread's exclusive offset
#pragma unroll
    for (int q = 0; q < 10; ++q) {
        int i = base + q;
        if (i < n) ptr[i] = tbase + loc[q];
    }
}

// Scatter without atomics: pos = ptr[col] + precomputed slot.
__global__ __launch_bounds__(256) void scatter_kernel(const int* __restrict__ row,
                                                      const int* __restrict__ col,
                                                      const float* __restrict__ ew,
                                                      const float* __restrict__ dinv,
                                                      const int* __restrict__ ptr,
                                                      const int* __restrict__ slot,
                                                      int* __restrict__ csr_src,
                                                      float* __restrict__ csr_w, int e) {
    int i = blockIdx.x * 256 + threadIdx.x;
    if (i < e) {
        int c = col[i], r = row[i];
        int pos = ptr[c] + slot[i];
        csr_src[pos] = r;
        csr_w[pos] = dinv[r] * ew[i] * dinv[c];
    }
}

// ---------------------------------------------------------------------------
// XCD-sliced aggregation over PACKED fp16 activations, fp16 output:
//   acc[n,f] = dinv[n]^2 * x[n,f] + sum_in w * x[src,f]   (fp32 accumulate)
// One WAVE per (node, 64-PAIR slice = 128 features); lane = one u32 pair.
// Slab per slice = 10000 x 128 x 2B = 2.56 MB < 4 MB per-XCD L2.
// 256-thr blocks, 4 waves = 4 consecutive NODES of the SAME slice:
//   slice = blockIdx & (NS-1); node = (blockIdx>>SSHIFT)*4 + waveid.
// Since NS | 8, blockIdx mod 8 (round-robin XCD dispatch) fixes the slice
// per XCD -> each XCD L2 holds exactly one slab, same affinity as the
// original wave-per-block layout.  [R1/R2/R3 lesson: packaging that mixes
// slices inside a block puts the FULL activation array in every XCD's L2]
// node via readfirstlane -> scalar CSR metadata, gather bases in SGPRs.
// ---------------------------------------------------------------------------
template <int F, int SSHIFT>
__global__ __launch_bounds__(256) void agg_slice_kernel(const unsigned int* __restrict__ xpk,
                                                        const int* __restrict__ ptr,
                                                        const int* __restrict__ csr_src,
                                                        const float* __restrict__ csr_w,
                                                        const float* __restrict__ dinv,
                                                        unsigned int* __restrict__ o) {
    constexpr int F2 = F / 2;
    const int b = (int)blockIdx.x;
    const int slice = b & ((1 << SSHIFT) - 1);    // block-uniform
    const int node = __builtin_amdgcn_readfirstlane(
        (b >> SSHIFT) * 4 + ((int)threadIdx.x >> 6));
    const int lane = (int)threadIdx.x & 63;
    const int f2 = slice * 64 + lane;             // pair index
    const float di = dinv[node];
    const float si = di * di;
    unsigned int gs = xpk[node * F2 + f2];
    float acc0 = si * h2f_lo(gs);
    float acc1 = si * h2f_hi(gs);
    const int s = ptr[node], e = ptr[node + 1];   // 8-aligned, length % 8 == 0

    for (int j = s; j < e; j += 8) {
        // uniform indices -> s_load_dwordx4; weights land in SGPRs
        int4   sa = *(const int4*)(csr_src + j);
        int4   sb = *(const int4*)(csr_src + j + 4);
        float4 wa = *(const float4*)(csr_w + j);
        float4 wb = *(const float4*)(csr_w + j + 4);
        // 8 independent dword gathers in flight (scalar bases)
        unsigned int g0 = xpk[sa.x * F2 + f2];
        unsigned int g1 = xpk[sa.y * F2 + f2];
        unsigned int g2 = xpk[sa.z * F2 + f2];
        unsigned int g3 = xpk[sa.w * F2 + f2];
        unsigned int g4 = xpk[sb.x * F2 + f2];
        unsigned int g5 = xpk[sb.y * F2 + f2];
        unsigned int g6 = xpk[sb.z * F2 + f2];
        unsigned int g7 = xpk[sb.w * F2 + f2];
        acc0 += wa.x * h2f_lo(g0) + wa.y * h2f_lo(g1) + wa.z * h2f_lo(g2) + wa.w * h2f_lo(g3);
        acc1 += wa.x * h2f_hi(g0) + wa.y * h2f_hi(g1) + wa.z * h2f_hi(g2) + wa.w * h2f_hi(g3);
        acc0 += wb.x * h2f_lo(g4) + wb.y * h2f_lo(g5) + wb.z * h2f_lo(g6) + wb.w * h2f_lo(g7);
        acc1 += wb.x * h2f_hi(g4) + wb.y * h2f_hi(g5) + wb.z * h2f_hi(g6) + wb.w * h2f_hi(g7);
    }

    unsigned short h0 = f2h_bits(acc0);
    unsigned short h1 = f2h_bits(acc1);
    o[node * F2 + f2] = ((unsigned int)h1 << 16) | h0;
}

// ---------------------------------------------------------------------------
// fp16 MFMA GEMM + bias + relu, async global->LDS staging, fp16 output.
//   C[M,N] = A[M,K] @ B[K,N] + bias   (fp32 accumulate, single pass)
// B transposed as Bt[N][K]; A row-padded to TM multiple (pad rows discarded).
// Tile 128m x 128n, BK=32, 256 threads = 4 waves of 64m x 64n.
// LDS 16KB/buf x 2 = 32KB -> 3 blocks/CU.
// ---------------------------------------------------------------------------
typedef _Float16 half8 __attribute__((ext_vector_type(8)));
typedef float f32x4 __attribute__((ext_vector_type(4)));

#define TM 128
#define TN 128
#define BK 32
#define LDS_A 0
#define LDS_B 8192
#define LDS_BUF 16384

__device__ __forceinline__ void async16(const unsigned short* g, unsigned char* l) {
    __builtin_amdgcn_global_load_lds(
        (const __attribute__((address_space(1))) unsigned int*)g,
        (__attribute__((address_space(3))) unsigned int*)l, 16, 0, 0);
}

__global__ __launch_bounds__(256, 3) void gemm_mfma_kernel(
        const unsigned short* __restrict__ A,
        const unsigned short* __restrict__ Bt,
        const float* __restrict__ bias,
        unsigned short* __restrict__ Cb,
        int M, int K, int N) {
    __shared__ unsigned char lds[2 * LDS_BUF];
    const int t = (int)threadIdx.x;

    // bijective XCD-chunked remap (m204): same-row-panel tiles share an XCD L2
    const int gx = (int)gridDim.x;
    const int nwg = gx * (int)gridDim.y;
    const int lin = (int)blockIdx.y * gx + (int)blockIdx.x;
    const int xcd = lin & 7, idx = lin >> 3;
    const int q = nwg >> 3, r = nwg & 7;
    const int logi = (xcd < r ? xcd * (q + 1) : r * (q + 1) + (xcd - r) * q) + idx;
    const int bm = (logi / gx) * TM;
    const int bn = (logi % gx) * TN;

    const int lane = t & 63;
    const int wave = t >> 6;
    const int wm = (wave & 1) * 64;
    const int wn = (wave >> 1) * 64;

    // ---- staging geometry (per lane): 16-row blocks, 1024 B per async issue ----
    const int slr = lane >> 2;                       // 0..15 local row
    const int scc = (lane & 3) ^ ((slr >> 1) & 3);   // swizzled global chunk
    const int bi0 = wave * 2, bi1 = wave * 2 + 1;    // 16-row block ids (0..7)
    const unsigned short* gA0 = A + (size_t)(bm + bi0 * 16 + slr) * K + scc * 8;
    const unsigned short* gA1 = A + (size_t)(bm + bi1 * 16 + slr) * K + scc * 8;
    const unsigned short* gB0 = Bt + (size_t)(bn + bi0 * 16 + slr) * K + scc * 8;
    const unsigned short* gB1 = Bt + (size_t)(bn + bi1 * 16 + slr) * K + scc * 8;

    // ---- fragment read geometry ----
    const int quad = lane >> 4;
    const int lr16 = lane & 15;
    const int fs = (quad ^ ((lr16 >> 1) & 3)) * 16;  // swizzled slot byte offset

    f32x4 acc[4][4];
    const f32x4 zero4 = {0.f, 0.f, 0.f, 0.f};
#pragma unroll
    for (int i = 0; i < 4; ++i)
#pragma unroll
        for (int j = 0; j < 4; ++j) acc[i][j] = zero4;

    const int KT = K / BK;

    auto stage = [&](int kt, int buf) {
        const int k0 = kt * BK;
        unsigned char* b = &lds[buf * LDS_BUF];
        async16(gA0 + k0, b + LDS_A + bi0 * 1024);
        async16(gA1 + k0, b + LDS_A + bi1 * 1024);
        async16(gB0 + k0, b + LDS_B + bi0 * 1024);
        async16(gB1 + k0, b + LDS_B + bi1 * 1024);
    };

    stage(0, 0);
    __syncthreads();

    for (int kt = 0; kt < KT; ++kt) {
        const int buf = kt & 1;
        if (kt + 1 < KT) stage(kt + 1, buf ^ 1);   // async, drains at barrier below

        unsigned char* b = &lds[buf * LDS_BUF];
        half8 av[4], bv[4];
#pragma unroll
        for (int i = 0; i < 4; ++i) {
            int ro = (wm + i * 16 + lr16) * 64 + fs;
            av[i] = *(const half8*)(b + LDS_A + ro);
        }
#pragma unroll
        for (int j = 0; j < 4; ++j) {
            int ro = (wn + j * 16 + lr16) * 64 + fs;
            bv[j] = *(const half8*)(b + LDS_B + ro);
        }
#pragma unroll
        for (int i = 0; i < 4; ++i)
#pragma unroll
            for (int j = 0; j < 4; ++j)
                acc[i][j] = __builtin_amdgcn_mfma_f32_16x16x32_f16(av[i], bv[j], acc[i][j], 0, 0, 0);
        __syncthreads();
    }

    // epilogue: bias + relu, store fp16
    float bcol[4];
#pragma unroll
    for (int j = 0; j < 4; ++j) bcol[j] = bias[bn + wn + j * 16 + lr16];
#pragma unroll
    for (int i = 0; i < 4; ++i) {
#pragma unroll
        for (int r2 = 0; r2 < 4; ++r2) {
            int m = bm + wm + i * 16 + quad * 4 + r2;
            if (m < M) {
#pragma unroll
                for (int j = 0; j < 4; ++j) {
                    float vv = fmaxf(acc[i][j][r2] + bcol[j], 0.f);
                    Cb[(size_t)m * N + bn + wn + j * 16 + lr16] = f2h_bits(vv);
                }
            }
        }
    }
}

// ---------------------------------------------------------------------------
// GEMM for layer 3: N=8, K=768, A packed fp16 pairs.  One wave per row.
// ---------------------------------------------------------------------------
__global__ __launch_bounds__(64) void gemm_n8_kernel(const unsigned int* __restrict__ Apk,
                                                     const float* __restrict__ B,
                                                     float* __restrict__ C) {
    const int m = blockIdx.x;
    const int lane = (int)threadIdx.x;
    const unsigned int* a = Apk + m * 384;   // 384 pairs = 768 feats
    float acc[8] = {};
#pragma unroll
    for (int it = 0; it < 6; ++it) {
        int j2 = lane + it * 64;
        unsigned int av = a[j2];
        float a0 = h2f_lo(av), a1 = h2f_hi(av);
        const float* B0 = B + (size_t)(2 * j2) * 8;
        float4 p0 = *(const float4*)(B0);
        float4 p1 = *(const float4*)(B0 + 4);
        float4 q0 = *(const float4*)(B0 + 8);
        float4 q1 = *(const float4*)(B0 + 12);
        acc[0] += a0 * p0.x + a1 * q0.x; acc[1] += a0 * p0.y + a1 * q0.y;
        acc[2] += a0 * p0.z + a1 * q0.z; acc[3] += a0 * p0.w + a1 * q0.w;
        acc[4] += a0 * p1.x + a1 * q1.x; acc[5] += a0 * p1.y + a1 * q1.y;
        acc[6] += a0 * p1.z + a1 * q1.z; acc[7] += a0 * p1.w + a1 * q1.w;
    }
#pragma unroll
    for (int off = 32; off > 0; off >>= 1) {
#pragma unroll
        for (int i = 0; i < 8; ++i) acc[i] += __shfl_down(acc[i], off);
    }
    if (lane == 0) {
#pragma unroll
        for (int i = 0; i < 8; ++i) C[(size_t)m * 8 + i] = acc[i];
    }
}

// Aggregation for fout=8 (final layer, +bias): one wave per node, lanes split edges.
__global__ __launch_bounds__(64) void agg8_kernel(const float* __restrict__ xw,
                                                  const int* __restrict__ ptr,
                                                  const int* __restrict__ csr_src,
                                                  const float* __restrict__ csr_w,
                                                  const float* __restrict__ dinv,
                                                  const float* __restrict__ bias,
                                                  float* __restrict__ out) {
    int node = blockIdx.x;
    int lane = threadIdx.x;
    float acc[8] = {};
    int s = ptr[node], e = ptr[node + 1];
    for (int j = s + lane; j < e; j += 64) {
        int src = csr_src[j];
        float w = csr_w[j];
        float4 g0 = *(const float4*)(xw + (size_t)src * 8);
        float4 g1 = *(const float4*)(xw + (size_t)src * 8 + 4);
        acc[0] += w * g0.x; acc[1] += w * g0.y; acc[2] += w * g0.z; acc[3] += w * g0.w;
        acc[4] += w * g1.x; acc[5] += w * g1.y; acc[6] += w * g1.z; acc[7] += w * g1.w;
    }
#pragma unroll
    for (int off = 32; off > 0; off >>= 1) {
#pragma unroll
        for (int i = 0; i < 8; ++i) acc[i] += __shfl_down(acc[i], off);
    }
    if (lane == 0) {
        float di = dinv[node];
        float si = di * di;
#pragma unroll
        for (int i = 0; i < 8; ++i)
            out[(size_t)node * 8 + i] = acc[i] + si * xw[(size_t)node * 8 + i] + bias[i];
    }
}

// ---------------------------------------------------------------------------

extern "C" void kernel_launch(void* const* d_in, const int* in_sizes, int n_in,
                              void* d_out, int out_size, void* d_ws, size_t ws_size,
                              hipStream_t stream) {
    const int N = N_NODES, E = N_EDGES;
    const int N_PAD = ((N + TM - 1) / TM) * TM;   // 10112
    const float* x   = (const float*)d_in[0];
    const int*   ei  = (const int*)d_in[1];   // [2, E] (row=source, col=target)
    const float* ew  = (const float*)d_in[2];
    const float* W1  = (const float*)d_in[3];
    const float* b1  = (const float*)d_in[4];
    const float* W2  = (const float*)d_in[5];
    const float* b2  = (const float*)d_in[6];
    const float* W3  = (const float*)d_in[7];
    const float* b3  = (const float*)d_in[8];
    float* out = (float*)d_out;

    const int* row = ei;        // source
    const int* col = ei + E;    // target

    // workspace layout (256B-aligned); ~47 MB total
    char* ws = (char*)d_ws;
    size_t off = 0;
    auto alloc = [&](size_t bytes) {
        void* p = ws + off;
        off += (bytes + 255) & ~(size_t)255;
        return p;
    };
    float*          deg     = (float*)alloc((size_t)N * 4);
    float*          dinv    = (float*)alloc((size_t)N * 4);
    int*            counts  = (int*)alloc((size_t)N * 4);
    int*            col_ptr = (int*)alloc((size_t)(N + 1) * 4);
    int*            slot    = (int*)alloc((size_t)E * 4);
    int*            csr_src = (int*)alloc((size_t)E_PAD * 4);
    float*          csr_w   = (float*)alloc((size_t)E_PAD * 4);
    unsigned short* xh      = (unsigned short*)alloc((size_t)N * 256 * 2);   // x as fp16
    unsigned short* h1h     = (unsigned short*)alloc((size_t)N * 512 * 2);   // gemm1 out fp16
    unsigned short* h2h     = (unsigned short*)alloc((size_t)N * 768 * 2);   // gemm2 out fp16
    unsigned short* Aagg    = (unsigned short*)alloc((size_t)N_PAD * 512 * 2); // agg out (both layers)
    unsigned short* W1t     = (unsigned short*)alloc((size_t)512 * 256 * 2);
    unsigned short* W2t     = (unsigned short*)alloc((size_t)768 * 512 * 2);
    float*          xw8     = (float*)alloc((size_t)N * 8 * 4);
    (void)ws_size;

    int nb_edges = (E + 255) / 256;

    // --- fused setup (init + CSR zero + x->fp16 + weight conversion) ---
    {
        int tot = N + E_PAD + N * 256 + 256 * 512 + 512 * 768;
        setup_kernel<<<(tot + 255) / 256, 256, 0, stream>>>(
            deg, counts, csr_src, csr_w, x, xh, W1, W1t, W2, W2t);
    }
    count_slot_kernel<<<nb_edges, 256, 0, stream>>>(col, ew, deg, counts, slot, E);
    scan_dinv_kernel<<<1, 1024, 0, stream>>>(counts, col_ptr, deg, dinv, N);
    scatter_kernel<<<nb_edges, 256, 0, stream>>>(row, col, ew, dinv, col_ptr, slot,
                                                 csr_src, csr_w, E);

    // --- layer 1: agg(fp16 x, 2 slices) -> gemm 256->512 (+b1, relu, fp16 out)
    agg_slice_kernel<256, 1><<<N * 2 / 4, 256, 0, stream>>>(
        (const unsigned int*)xh, col_ptr, csr_src, csr_w, dinv, (unsigned int*)Aagg);
    {
        dim3 grid(512 / TN, N_PAD / TM);
        gemm_mfma_kernel<<<grid, 256, 0, stream>>>(Aagg, W1t, b1, h1h, N, 256, 512);
    }
    // --- layer 2: agg(fp16 h1, 4 slices) -> gemm 512->768 (+b2, relu, fp16 out)
    agg_slice_kernel<512, 2><<<N * 4 / 4, 256, 0, stream>>>(
        (const unsigned int*)h1h, col_ptr, csr_src, csr_w, dinv, (unsigned int*)Aagg);
    {
        dim3 grid(768 / TN, N_PAD / TM);
        gemm_mfma_kernel<<<grid, 256, 0, stream>>>(Aagg, W2t, b2, h2h, N, 512, 768);
    }
    // --- layer 3: gemm 768->8 (packed fp16 A) -> agg8 (+b3) ---
    gemm_n8_kernel<<<N, 64, 0, stream>>>((const unsigned int*)h2h, W3, xw8);
    agg8_kernel<<<N, 64, 0, stream>>>(xw8, col_ptr, csr_src, csr_w, dinv, b3, out);

    (void)out_size; (void)n_in; (void)in_sizes;
}